// Round 8
// baseline (451.361 us; speedup 1.0000x reference)
//
#include <hip/hip_runtime.h>
#include <hip/hip_bf16.h>

#define B_N  128
#define VIS  4096
#define HID  4096
#define EMB  512
#define NNEG 2048
#define OUTN (NNEG + 1)
#define SPLIT1 8
#define SPLIT2 16
#define NBLK 512u

using f32x4  = __attribute__((ext_vector_type(4))) float;
using f32x2  = __attribute__((ext_vector_type(2))) float;
using bf16x8 = __attribute__((ext_vector_type(8))) short;

// HW packed f32x2 -> bf16x2 (v_cvt_pk_bf16_f32 on gfx950), RNE.
static __device__ __forceinline__ unsigned pk2bf(float x, float y) {
  union { __hip_bfloat162 h; unsigned u; } c;
  c.h = __float22bfloat162_rn(make_float2(x, y));
  return c.u;
}

// LDS-only drain + barrier: global loads stay in flight across it.
#define PIPE_BARRIER() __asm__ volatile("s_waitcnt lgkmcnt(0)\n\ts_barrier" ::: "memory")

// R16: software grid barrier (R15's hipLaunchCooperativeKernel silently failed
// under the harness's stream capture -> kernel never ran, out stayed zero).
// Co-residency contract: launch_bounds(512,4) -> <=128 VGPR -> 2 blocks/CU;
// LDS 36.9KB -> 4/CU cap; grid 512 = 2 x 256 CUs exactly => all blocks
// resident, spin barrier cannot deadlock. Per-phase counter (no reset/sense);
// counters zeroed by a 16B hipMemsetAsync before launch (graph-capturable).
// __syncthreads drains each wave's stores (vmcnt0 before s_barrier); thread-0
// agent-scope fences do the cross-XCD L2 writeback/invalidate.
static __device__ __forceinline__ void gbar(unsigned* bar, int ph) {
  __syncthreads();
  if (threadIdx.x == 0) {
    __threadfence();                                   // release: L2 writeback
    __hip_atomic_fetch_add(&bar[ph], 1u, __ATOMIC_RELEASE, __HIP_MEMORY_SCOPE_AGENT);
    while (__hip_atomic_load(&bar[ph], __ATOMIC_ACQUIRE, __HIP_MEMORY_SCOPE_AGENT) < NBLK)
      __builtin_amdgcn_s_sleep(2);
    __threadfence();                                   // acquire: L2 invalidate
  }
  __syncthreads();
}

// Single fused kernel. Phase bodies byte-identical math to the verified
// 155us 5-kernel chain (R13/R14); see per-phase comments there.
__global__ __launch_bounds__(512, 4) void mega_kernel(
    const float* __restrict__ vfs, const float* __restrict__ p_lfs,
    const float* __restrict__ n_lfs, const float* __restrict__ Wh,
    const float* __restrict__ bh, const float* __restrict__ We,
    const float* __restrict__ be, float* __restrict__ out,
    float* __restrict__ Hp, float* __restrict__ emb,
    unsigned short* __restrict__ Abf, unsigned short* __restrict__ Hbf,
    unsigned* __restrict__ bar) {

  __shared__ __align__(16) char smem[16 * 576 * 4];   // 36,864 B phase arena

  const int bid = blockIdx.x, t = threadIdx.x;
  const int gid = bid * 512 + t;                      // [0, 262144)

  // ---------------- P0: prep — vfs fp32 -> Abf bf16; zero emb ----------------
  {
    float2 a = ((const float2*)vfs)[gid];             // 524288 floats, 2/thread
    ((unsigned*)Abf)[gid] = pk2bf(a.x, a.y);
    if (gid < (B_N * EMB / 4))
      ((float4*)emb)[gid] = make_float4(0.f, 0.f, 0.f, 0.f);
  }
  gbar(bar, 0);

  // ---------------- P1: gemm1 (verified R9 config, bid-decomposed) -----------
  // Hp[split][128][4096] = vfs(bf16) @ W_h^T (+b_h on split 0).
  // bx = bid&63 (64 n-tiles), by = bid>>6 (8 splits). BM=128,BN=64,BK=64.
  {
    const int bx = bid & 63, by = bid >> 6;
    const int n0    = bx * 64;
    const int kbase = by * 512;
    unsigned short* Wsb = (unsigned short*)smem;      // [2][64*64], XOR-swizzled

    const int w = t >> 6, lane = t & 63;
    const int m_lane = lane & 15, kq = lane >> 4;
    f32x4 acc[4] = {};

    const int wr = t >> 3, wg = t & 7;
    const float* Wg = Wh + (size_t)(n0 + wr) * VIS + kbase + wg * 8;
    const int wofs = wr * 64 + ((wg ^ (wr & 7)) * 8);

    const unsigned short* Ag = Abf + (size_t)(w * 16 + m_lane) * VIS + kbase + kq * 8;

    float4 wva[8], wvb[8];   // entire W chunk, issued up front
#pragma unroll
    for (int i = 0; i < 8; ++i) {
      wva[i] = *(const float4*)(Wg + i * 64);
      wvb[i] = *(const float4*)(Wg + i * 64 + 4);
    }

    bf16x8 av[3][2];         // A tiles, rotating [slot][ks]
    av[0][0] = *(const bf16x8*)(Ag);
    av[0][1] = *(const bf16x8*)(Ag + 32);
    av[1][0] = *(const bf16x8*)(Ag + 64);
    av[1][1] = *(const bf16x8*)(Ag + 96);

    {
      uint4 pk;
      pk.x = pk2bf(wva[0].x, wva[0].y); pk.y = pk2bf(wva[0].z, wva[0].w);
      pk.z = pk2bf(wvb[0].x, wvb[0].y); pk.w = pk2bf(wvb[0].z, wvb[0].w);
      *(uint4*)&Wsb[wofs] = pk;
    }
    PIPE_BARRIER();

#pragma unroll
    for (int k = 0; k < 8; ++k) {
      const int cur = k & 1;
      if (k + 2 < 8) {
        av[(k + 2) % 3][0] = *(const bf16x8*)(Ag + (k + 2) * 64);
        av[(k + 2) % 3][1] = *(const bf16x8*)(Ag + (k + 2) * 64 + 32);
      }
      if (k + 1 < 8) {
        uint4 pk;
        pk.x = pk2bf(wva[k + 1].x, wva[k + 1].y); pk.y = pk2bf(wva[k + 1].z, wva[k + 1].w);
        pk.z = pk2bf(wvb[k + 1].x, wvb[k + 1].y); pk.w = pk2bf(wvb[k + 1].z, wvb[k + 1].w);
        *(uint4*)&Wsb[(1 - cur) * 4096 + wofs] = pk;
      }
#pragma unroll
      for (int ks = 0; ks < 2; ++ks) {
        const int Gk = ks * 4 + kq;
        const bf16x8 a = av[k % 3][ks];
#pragma unroll
        for (int ni = 0; ni < 4; ++ni) {
          const int c = m_lane + ni * 16;
          bf16x8 b = *(const bf16x8*)&Wsb[cur * 4096 + c * 64 + ((Gk ^ (c & 7)) * 8)];
          acc[ni] = __builtin_amdgcn_mfma_f32_16x16x32_bf16(a, b, acc[ni], 0, 0, 0);
        }
      }
      PIPE_BARRIER();
    }

    float* Pd = Hp + (size_t)by * (B_N * HID);
    const int rq = (lane >> 4) * 4;
#pragma unroll
    for (int ni = 0; ni < 4; ++ni) {
      const int ng = n0 + ni * 16 + m_lane;
      const float bias = (by == 0) ? bh[ng] : 0.0f;
#pragma unroll
      for (int r = 0; r < 4; ++r)
        Pd[(size_t)(w * 16 + rq + r) * HID + ng] = acc[ni][r] + bias;
    }
  }
  gbar(bar, 1);

  // ---------------- P2: cvt — Hbf = bf16(sum of 8 Hp planes) -----------------
  {
    const size_t PS2 = (size_t)B_N * HID / 2;
    const float2* hp2 = (const float2*)Hp;
    float2 a = hp2[gid];
#pragma unroll
    for (int p = 1; p < SPLIT1; ++p) {
      float2 v = hp2[gid + p * PS2];
      a.x += v.x; a.y += v.y;
    }
    ((unsigned*)Hbf)[gid] = pk2bf(a.x, a.y);
  }
  gbar(bar, 2);

  // ---------------- P3: gemm2 (verified R11 config, bid-decomposed) ----------
  // emb += hidden(bf16) @ W_e^T (+b_e split 0), fp32 atomics.
  // bx = bid&31 (32 n-tiles), by = bid>>5 (16 splits).
  {
    const int bx = bid & 31, by = bid >> 5;
    const int n0    = bx * 16;
    const int kbase = by * 256;
    unsigned short* Wsb = (unsigned short*)smem;      // [2][16*64]

    const int w = t >> 6, lane = t & 63;
    const int m_lane = lane & 15, kq = lane >> 4;
    f32x4 acc = {};

    const int wr = t >> 5, e = (t & 31) * 2;
    const float* Wg = We + (size_t)(n0 + wr) * HID + kbase + e;
    const int wofs = wr * 64 + (((e >> 3) ^ (wr & 7)) * 8) + (e & 7);

    const unsigned short* Ag = Hbf + (size_t)(w * 16 + m_lane) * HID + kbase + kq * 8;

    float2 wv[4];
#pragma unroll
    for (int i = 0; i < 4; ++i) wv[i] = *(const float2*)(Wg + i * 64);

    bf16x8 av[3][2];
    av[0][0] = *(const bf16x8*)(Ag);
    av[0][1] = *(const bf16x8*)(Ag + 32);
    av[1][0] = *(const bf16x8*)(Ag + 64);
    av[1][1] = *(const bf16x8*)(Ag + 96);

    *(unsigned*)&Wsb[wofs] = pk2bf(wv[0].x, wv[0].y);
    PIPE_BARRIER();

#pragma unroll
    for (int k = 0; k < 4; ++k) {
      const int cur = k & 1;
      if (k + 2 < 4) {
        av[(k + 2) % 3][0] = *(const bf16x8*)(Ag + (k + 2) * 64);
        av[(k + 2) % 3][1] = *(const bf16x8*)(Ag + (k + 2) * 64 + 32);
      }
      if (k + 1 < 4) {
        const float2 wc = wv[k + 1];
        *(unsigned*)&Wsb[(1 - cur) * 1024 + wofs] = pk2bf(wc.x, wc.y);
      }
#pragma unroll
      for (int ks = 0; ks < 2; ++ks) {
        const int Gk = ks * 4 + kq;
        bf16x8 b0 = *(const bf16x8*)&Wsb[cur * 1024 + m_lane * 64 + ((Gk ^ (m_lane & 7)) * 8)];
        acc = __builtin_amdgcn_mfma_f32_16x16x32_bf16(av[k % 3][ks], b0, acc, 0, 0, 0);
      }
      PIPE_BARRIER();
    }

    const int rq = (lane >> 4) * 4;
    const int ng = n0 + m_lane;
    const float bias = (by == 0) ? be[ng] : 0.0f;
#pragma unroll
    for (int r = 0; r < 4; ++r)
      atomicAdd(&emb[(w * 16 + rq + r) * EMB + ng], acc[r] + bias);
  }
  gbar(bar, 3);

  // ---------------- P4: score (verified body, 32 b-rows/block) ---------------
  // All 512 blocks: 32 b x 16 negatives. Blocks 0..7 additionally: positives.
  {
    float* nl = (float*)smem;                         // [16][576]
    const int s = t & 15, tb = t >> 4;                // tb in [0,32)
    const int n0 = (bid >> 2) * 16, b0 = (bid & 3) * 32;
    const f32x2 z2 = {0.f, 0.f};

#pragma unroll
    for (int i = 0; i < 4; ++i) {                     // stage 16 negative rows
      const int f = t + i * 512;
      const int r = f >> 7, o4 = f & 127;
      float4 v = *(const float4*)(n_lfs + (size_t)(n0 + r) * EMB + o4 * 4);
      *(float4*)&nl[r * 576 + (o4 >> 3) * 36 + (o4 & 7) * 4] = v;
    }
    const float* eb = emb + (size_t)(b0 + tb) * EMB + s * 32;
    f32x2 ev[16];
#pragma unroll
    for (int i = 0; i < 8; ++i) {
      float4 v = *(const float4*)(eb + i * 4);
      ev[2 * i]     = (f32x2){v.x, v.y};
      ev[2 * i + 1] = (f32x2){v.z, v.w};
    }
    __syncthreads();

    for (int j = 0; j < 16; ++j) {
      const float* nr = &nl[j * 576 + s * 36];
      f32x2 a0 = z2, a1 = z2;
#pragma unroll
      for (int i = 0; i < 8; ++i) {
        float4 nv = *(const float4*)(nr + i * 4);
        f32x2 d0 = (f32x2){nv.x, nv.y} - ev[2 * i];
        f32x2 d1 = (f32x2){nv.z, nv.w} - ev[2 * i + 1];
        d0 = __builtin_elementwise_max(d0, z2);
        d1 = __builtin_elementwise_max(d1, z2);
        a0 = __builtin_elementwise_fma(d0, d0, a0);
        a1 = __builtin_elementwise_fma(d1, d1, a1);
      }
      float ss = (a0.x + a0.y) + (a1.x + a1.y);
      ss += __shfl_xor(ss, 1);
      ss += __shfl_xor(ss, 2);
      ss += __shfl_xor(ss, 4);
      ss += __shfl_xor(ss, 8);
      if (s == 0) out[(size_t)(b0 + tb) * OUTN + 1 + n0 + j] = -sqrtf(ss);
    }

    if (bid < 8 && tb < 16) {                         // positives: b = bid*16+tb
      const int b = bid * 16 + tb;
      const float* pb = p_lfs + (size_t)b * EMB + s * 32;
      const float* ebp = emb + (size_t)b * EMB + s * 32;
      f32x2 a0 = z2, a1 = z2;
#pragma unroll
      for (int i = 0; i < 8; ++i) {
        float4 pv = *(const float4*)(pb + i * 4);
        float4 evv = *(const float4*)(ebp + i * 4);
        f32x2 d0 = (f32x2){pv.x, pv.y} - (f32x2){evv.x, evv.y};
        f32x2 d1 = (f32x2){pv.z, pv.w} - (f32x2){evv.z, evv.w};
        d0 = __builtin_elementwise_max(d0, z2);
        d1 = __builtin_elementwise_max(d1, z2);
        a0 = __builtin_elementwise_fma(d0, d0, a0);
        a1 = __builtin_elementwise_fma(d1, d1, a1);
      }
      float ss = (a0.x + a0.y) + (a1.x + a1.y);
      ss += __shfl_xor(ss, 1);
      ss += __shfl_xor(ss, 2);
      ss += __shfl_xor(ss, 4);
      ss += __shfl_xor(ss, 8);
      if (s == 0) out[(size_t)b * OUTN] = -sqrtf(ss);
    }
  }
}

extern "C" void kernel_launch(void* const* d_in, const int* in_sizes, int n_in,
                              void* d_out, int out_size, void* d_ws, size_t ws_size,
                              hipStream_t stream) {
  const float* vfs   = (const float*)d_in[0];
  const float* p_lfs = (const float*)d_in[1];
  const float* n_lfs = (const float*)d_in[2];
  const float* W_h   = (const float*)d_in[3];
  const float* b_h   = (const float*)d_in[4];
  const float* W_e   = (const float*)d_in[5];
  const float* b_e   = (const float*)d_in[6];
  float* out = (float*)d_out;

  // ws layout (18.25 MB + 16 B): [Hp 8x2MB][emb 256KB][Abf 1MB][Hbf 1MB][bar]
  char* ws = (char*)d_ws;
  float*          Hp  = (float*)ws;
  float*          emb = (float*)(ws + (16u << 20));
  unsigned short* Abf = (unsigned short*)(ws + (16u << 20) + (256u << 10));
  unsigned short* Hbf = (unsigned short*)(ws + (17u << 20) + (256u << 10));
  unsigned*       bar = (unsigned*)(ws + (18u << 20) + (256u << 10));

  hipMemsetAsync(bar, 0, 4 * sizeof(unsigned), stream);
  mega_kernel<<<NBLK, 512, 0, stream>>>(vfs, p_lfs, n_lfs, W_h, b_h, W_e, b_e,
                                        out, Hp, emb, Abf, Hbf, bar);
}

// Round 10
// 305.331 us; speedup vs baseline: 1.4783x; 1.4783x over previous
//
#include <hip/hip_runtime.h>
#include <hip/hip_bf16.h>

#define B_N  128
#define VIS  4096
#define HID  4096
#define EMB  512
#define NNEG 2048
#define OUTN (NNEG + 1)
#define SPLIT1 8
#define SPLIT2 16
#define NBLK 512u

using f32x4  = __attribute__((ext_vector_type(4))) float;
using f32x2  = __attribute__((ext_vector_type(2))) float;
using bf16x8 = __attribute__((ext_vector_type(8))) short;

// HW packed f32x2 -> bf16x2 (v_cvt_pk_bf16_f32 on gfx950), RNE.
static __device__ __forceinline__ unsigned pk2bf(float x, float y) {
  union { __hip_bfloat162 h; unsigned u; } c;
  c.h = __float22bfloat162_rn(make_float2(x, y));
  return c.u;
}

// LDS-only drain + barrier: global loads stay in flight across it.
#define PIPE_BARRIER() __asm__ volatile("s_waitcnt lgkmcnt(0)\n\ts_barrier" ::: "memory")

// scalar keep-alive (32-bit "v" operands only — float4 as asm input is
// rejected by gfx950 clang: "indirect register inputs")
#define KEEP4(v) asm volatile("" :: "v"((v).x), "v"((v).y), "v"((v).z), "v"((v).w))
#define KEEP2(v) asm volatile("" :: "v"((v).x), "v"((v).y))

// R17 barrier fix. R16 measured 372us (vs ~33us of work): the spin used an
// ACQUIRE agent load, which emits buffer_inv (full L2 invalidate) EVERY poll
// -> 512 pollers x 4 barriers = invalidate storm (HBM 240GB/s, VALUBusy 3%).
// Fix: RELAXED spin (agent-scope bits alone bypass local L2 and observe the
// remote update; no per-poll cache maintenance), ONE release fence before the
// add (local L2 writeback so other XCDs see our stores), ONE acquire fence
// after the loop (invalidate once). s_sleep(16) ~ 1k cycles/poll.
static __device__ __forceinline__ void gbar(unsigned* bar, int ph) {
  __syncthreads();
  if (threadIdx.x == 0) {
    __builtin_amdgcn_fence(__ATOMIC_RELEASE, "agent");   // one wbl2
    __hip_atomic_fetch_add(&bar[ph], 1u, __ATOMIC_RELAXED, __HIP_MEMORY_SCOPE_AGENT);
    while (__hip_atomic_load(&bar[ph], __ATOMIC_RELAXED, __HIP_MEMORY_SCOPE_AGENT) < NBLK)
      __builtin_amdgcn_s_sleep(16);
    __builtin_amdgcn_fence(__ATOMIC_ACQUIRE, "agent");   // one inv
  }
  __syncthreads();
}

// Single fused kernel. Phase bodies byte-identical math to the verified
// 155us 5-kernel chain (R13/R14). R17 second fix: R16's VGPR_Count=60 proved
// the gemm1 W-prologue (16 float4 = 64 live VGPRs) was sunk to just-before-use
// (R5 failure mode) -> latency-serial K-loop. Scalar asm keep-alives force the
// prefetch to materialize up front (guide rule #17).
__global__ __launch_bounds__(512, 4) void mega_kernel(
    const float* __restrict__ vfs, const float* __restrict__ p_lfs,
    const float* __restrict__ n_lfs, const float* __restrict__ Wh,
    const float* __restrict__ bh, const float* __restrict__ We,
    const float* __restrict__ be, float* __restrict__ out,
    float* __restrict__ Hp, float* __restrict__ emb,
    unsigned short* __restrict__ Abf, unsigned short* __restrict__ Hbf,
    unsigned* __restrict__ bar) {

  __shared__ __align__(16) char smem[16 * 576 * 4];   // 36,864 B phase arena

  const int bid = blockIdx.x, t = threadIdx.x;
  const int gid = bid * 512 + t;                      // [0, 262144)

  // ---------------- P0: prep — vfs fp32 -> Abf bf16; zero emb ----------------
  {
    float2 a = ((const float2*)vfs)[gid];             // 524288 floats, 2/thread
    ((unsigned*)Abf)[gid] = pk2bf(a.x, a.y);
    if (gid < (B_N * EMB / 4))
      ((float4*)emb)[gid] = make_float4(0.f, 0.f, 0.f, 0.f);
  }
  gbar(bar, 0);

  // ---------------- P1: gemm1 (verified R9 config, bid-decomposed) -----------
  // Hp[split][128][4096] = vfs(bf16) @ W_h^T (+b_h on split 0).
  // bx = bid&63 (64 n-tiles), by = bid>>6 (8 splits). BM=128,BN=64,BK=64.
  {
    const int bx = bid & 63, by = bid >> 6;
    const int n0    = bx * 64;
    const int kbase = by * 512;
    unsigned short* Wsb = (unsigned short*)smem;      // [2][64*64], XOR-swizzled

    const int w = t >> 6, lane = t & 63;
    const int m_lane = lane & 15, kq = lane >> 4;
    f32x4 acc[4] = {};

    const int wr = t >> 3, wg = t & 7;
    const float* Wg = Wh + (size_t)(n0 + wr) * VIS + kbase + wg * 8;
    const int wofs = wr * 64 + ((wg ^ (wr & 7)) * 8);

    const unsigned short* Ag = Abf + (size_t)(w * 16 + m_lane) * VIS + kbase + kq * 8;

    float4 wva[8], wvb[8];   // entire W chunk, issued up front (64 VGPRs)
#pragma unroll
    for (int i = 0; i < 8; ++i) {
      wva[i] = *(const float4*)(Wg + i * 64);
      wvb[i] = *(const float4*)(Wg + i * 64 + 4);
    }
    // keep-alive: force all 16 float4 to materialize here (defeats load
    // sinking; restores the measured R9 deep-prefetch schedule)
#pragma unroll
    for (int i = 0; i < 8; ++i) { KEEP4(wva[i]); KEEP4(wvb[i]); }

    bf16x8 av[3][2];         // A tiles, rotating [slot][ks]
    av[0][0] = *(const bf16x8*)(Ag);
    av[0][1] = *(const bf16x8*)(Ag + 32);
    av[1][0] = *(const bf16x8*)(Ag + 64);
    av[1][1] = *(const bf16x8*)(Ag + 96);

    {
      uint4 pk;
      pk.x = pk2bf(wva[0].x, wva[0].y); pk.y = pk2bf(wva[0].z, wva[0].w);
      pk.z = pk2bf(wvb[0].x, wvb[0].y); pk.w = pk2bf(wvb[0].z, wvb[0].w);
      *(uint4*)&Wsb[wofs] = pk;
    }
    PIPE_BARRIER();

#pragma unroll
    for (int k = 0; k < 8; ++k) {
      const int cur = k & 1;
      if (k + 2 < 8) {
        av[(k + 2) % 3][0] = *(const bf16x8*)(Ag + (k + 2) * 64);
        av[(k + 2) % 3][1] = *(const bf16x8*)(Ag + (k + 2) * 64 + 32);
      }
      if (k + 1 < 8) {
        uint4 pk;
        pk.x = pk2bf(wva[k + 1].x, wva[k + 1].y); pk.y = pk2bf(wva[k + 1].z, wva[k + 1].w);
        pk.z = pk2bf(wvb[k + 1].x, wvb[k + 1].y); pk.w = pk2bf(wvb[k + 1].z, wvb[k + 1].w);
        *(uint4*)&Wsb[(1 - cur) * 4096 + wofs] = pk;
      }
#pragma unroll
      for (int ks = 0; ks < 2; ++ks) {
        const int Gk = ks * 4 + kq;
        const bf16x8 a = av[k % 3][ks];
#pragma unroll
        for (int ni = 0; ni < 4; ++ni) {
          const int c = m_lane + ni * 16;
          bf16x8 b = *(const bf16x8*)&Wsb[cur * 4096 + c * 64 + ((Gk ^ (c & 7)) * 8)];
          acc[ni] = __builtin_amdgcn_mfma_f32_16x16x32_bf16(a, b, acc[ni], 0, 0, 0);
        }
      }
      PIPE_BARRIER();
    }

    float* Pd = Hp + (size_t)by * (B_N * HID);
    const int rq = (lane >> 4) * 4;
#pragma unroll
    for (int ni = 0; ni < 4; ++ni) {
      const int ng = n0 + ni * 16 + m_lane;
      const float bias = (by == 0) ? bh[ng] : 0.0f;
#pragma unroll
      for (int r = 0; r < 4; ++r)
        Pd[(size_t)(w * 16 + rq + r) * HID + ng] = acc[ni][r] + bias;
    }
  }
  gbar(bar, 1);

  // ---------------- P2: cvt — Hbf = bf16(sum of 8 Hp planes) -----------------
  {
    const size_t PS2 = (size_t)B_N * HID / 2;
    const float2* hp2 = (const float2*)Hp;
    float2 a = hp2[gid];
#pragma unroll
    for (int p = 1; p < SPLIT1; ++p) {
      float2 v = hp2[gid + p * PS2];
      a.x += v.x; a.y += v.y;
    }
    ((unsigned*)Hbf)[gid] = pk2bf(a.x, a.y);
  }
  gbar(bar, 2);

  // ---------------- P3: gemm2 (verified R11 config, bid-decomposed) ----------
  // emb += hidden(bf16) @ W_e^T (+b_e split 0), fp32 atomics.
  // bx = bid&31 (32 n-tiles), by = bid>>5 (16 splits).
  {
    const int bx = bid & 31, by = bid >> 5;
    const int n0    = bx * 16;
    const int kbase = by * 256;
    unsigned short* Wsb = (unsigned short*)smem;      // [2][16*64]

    const int w = t >> 6, lane = t & 63;
    const int m_lane = lane & 15, kq = lane >> 4;
    f32x4 acc = {};

    const int wr = t >> 5, e = (t & 31) * 2;
    const float* Wg = We + (size_t)(n0 + wr) * HID + kbase + e;
    const int wofs = wr * 64 + (((e >> 3) ^ (wr & 7)) * 8) + (e & 7);

    const unsigned short* Ag = Hbf + (size_t)(w * 16 + m_lane) * HID + kbase + kq * 8;

    float2 wv[4];
#pragma unroll
    for (int i = 0; i < 4; ++i) wv[i] = *(const float2*)(Wg + i * 64);
#pragma unroll
    for (int i = 0; i < 4; ++i) KEEP2(wv[i]);

    bf16x8 av[3][2];
    av[0][0] = *(const bf16x8*)(Ag);
    av[0][1] = *(const bf16x8*)(Ag + 32);
    av[1][0] = *(const bf16x8*)(Ag + 64);
    av[1][1] = *(const bf16x8*)(Ag + 96);

    *(unsigned*)&Wsb[wofs] = pk2bf(wv[0].x, wv[0].y);
    PIPE_BARRIER();

#pragma unroll
    for (int k = 0; k < 4; ++k) {
      const int cur = k & 1;
      if (k + 2 < 4) {
        av[(k + 2) % 3][0] = *(const bf16x8*)(Ag + (k + 2) * 64);
        av[(k + 2) % 3][1] = *(const bf16x8*)(Ag + (k + 2) * 64 + 32);
      }
      if (k + 1 < 4) {
        const float2 wc = wv[k + 1];
        *(unsigned*)&Wsb[(1 - cur) * 1024 + wofs] = pk2bf(wc.x, wc.y);
      }
#pragma unroll
      for (int ks = 0; ks < 2; ++ks) {
        const int Gk = ks * 4 + kq;
        bf16x8 b0 = *(const bf16x8*)&Wsb[cur * 1024 + m_lane * 64 + ((Gk ^ (m_lane & 7)) * 8)];
        acc = __builtin_amdgcn_mfma_f32_16x16x32_bf16(av[k % 3][ks], b0, acc, 0, 0, 0);
      }
      PIPE_BARRIER();
    }

    const int rq = (lane >> 4) * 4;
    const int ng = n0 + m_lane;
    const float bias = (by == 0) ? be[ng] : 0.0f;
#pragma unroll
    for (int r = 0; r < 4; ++r)
      atomicAdd(&emb[(w * 16 + rq + r) * EMB + ng], acc[r] + bias);
  }
  gbar(bar, 3);

  // ---------------- P4: score (verified body, 32 b-rows/block) ---------------
  // All 512 blocks: 32 b x 16 negatives. Blocks 0..7 additionally: positives.
  {
    float* nl = (float*)smem;                         // [16][576]
    const int s = t & 15, tb = t >> 4;                // tb in [0,32)
    const int n0 = (bid >> 2) * 16, b0 = (bid & 3) * 32;
    const f32x2 z2 = {0.f, 0.f};

#pragma unroll
    for (int i = 0; i < 4; ++i) {                     // stage 16 negative rows
      const int f = t + i * 512;
      const int r = f >> 7, o4 = f & 127;
      float4 v = *(const float4*)(n_lfs + (size_t)(n0 + r) * EMB + o4 * 4);
      *(float4*)&nl[r * 576 + (o4 >> 3) * 36 + (o4 & 7) * 4] = v;
    }
    const float* eb = emb + (size_t)(b0 + tb) * EMB + s * 32;
    f32x2 ev[16];
#pragma unroll
    for (int i = 0; i < 8; ++i) {
      float4 v = *(const float4*)(eb + i * 4);
      ev[2 * i]     = (f32x2){v.x, v.y};
      ev[2 * i + 1] = (f32x2){v.z, v.w};
    }
    __syncthreads();

    for (int j = 0; j < 16; ++j) {
      const float* nr = &nl[j * 576 + s * 36];
      f32x2 a0 = z2, a1 = z2;
#pragma unroll
      for (int i = 0; i < 8; ++i) {
        float4 nv = *(const float4*)(nr + i * 4);
        f32x2 d0 = (f32x2){nv.x, nv.y} - ev[2 * i];
        f32x2 d1 = (f32x2){nv.z, nv.w} - ev[2 * i + 1];
        d0 = __builtin_elementwise_max(d0, z2);
        d1 = __builtin_elementwise_max(d1, z2);
        a0 = __builtin_elementwise_fma(d0, d0, a0);
        a1 = __builtin_elementwise_fma(d1, d1, a1);
      }
      float ss = (a0.x + a0.y) + (a1.x + a1.y);
      ss += __shfl_xor(ss, 1);
      ss += __shfl_xor(ss, 2);
      ss += __shfl_xor(ss, 4);
      ss += __shfl_xor(ss, 8);
      if (s == 0) out[(size_t)(b0 + tb) * OUTN + 1 + n0 + j] = -sqrtf(ss);
    }

    if (bid < 8 && tb < 16) {                         // positives: b = bid*16+tb
      const int b = bid * 16 + tb;
      const float* pb = p_lfs + (size_t)b * EMB + s * 32;
      const float* ebp = emb + (size_t)b * EMB + s * 32;
      f32x2 a0 = z2, a1 = z2;
#pragma unroll
      for (int i = 0; i < 8; ++i) {
        float4 pv = *(const float4*)(pb + i * 4);
        float4 evv = *(const float4*)(ebp + i * 4);
        f32x2 d0 = (f32x2){pv.x, pv.y} - (f32x2){evv.x, evv.y};
        f32x2 d1 = (f32x2){pv.z, pv.w} - (f32x2){evv.z, evv.w};
        d0 = __builtin_elementwise_max(d0, z2);
        d1 = __builtin_elementwise_max(d1, z2);
        a0 = __builtin_elementwise_fma(d0, d0, a0);
        a1 = __builtin_elementwise_fma(d1, d1, a1);
      }
      float ss = (a0.x + a0.y) + (a1.x + a1.y);
      ss += __shfl_xor(ss, 1);
      ss += __shfl_xor(ss, 2);
      ss += __shfl_xor(ss, 4);
      ss += __shfl_xor(ss, 8);
      if (s == 0) out[(size_t)b * OUTN] = -sqrtf(ss);
    }
  }
}

extern "C" void kernel_launch(void* const* d_in, const int* in_sizes, int n_in,
                              void* d_out, int out_size, void* d_ws, size_t ws_size,
                              hipStream_t stream) {
  const float* vfs   = (const float*)d_in[0];
  const float* p_lfs = (const float*)d_in[1];
  const float* n_lfs = (const float*)d_in[2];
  const float* W_h   = (const float*)d_in[3];
  const float* b_h   = (const float*)d_in[4];
  const float* W_e   = (const float*)d_in[5];
  const float* b_e   = (const float*)d_in[6];
  float* out = (float*)d_out;

  // ws layout (18.25 MB + 16 B): [Hp 8x2MB][emb 256KB][Abf 1MB][Hbf 1MB][bar]
  char* ws = (char*)d_ws;
  float*          Hp  = (float*)ws;
  float*          emb = (float*)(ws + (16u << 20));
  unsigned short* Abf = (unsigned short*)(ws + (16u << 20) + (256u << 10));
  unsigned short* Hbf = (unsigned short*)(ws + (17u << 20) + (256u << 10));
  unsigned*       bar = (unsigned*)(ws + (18u << 20) + (256u << 10));

  hipMemsetAsync(bar, 0, 4 * sizeof(unsigned), stream);
  mega_kernel<<<NBLK, 512, 0, stream>>>(vfs, p_lfs, n_lfs, W_h, b_h, W_e, b_e,
                                        out, Hp, emb, Abf, Hbf, bar);
}